// Round 5
// baseline (12.954 us; speedup 1.0000x reference)
//
#include <hip/hip_runtime.h>

// Problem constants (from setup_inputs)
#define B_    16
#define S_    2048
#define T_    128
#define HD_   512
#define D2_   1024   // 2*hD
#define N_    64
#define NSPAN (B_ * N_)          // 1024 spans per set
#define SPAN_OUT (4 * HD_)       // 2048 floats per span
#define TOPIC_OUT (B_ * D2_)     // 16384 floats
#define SPB   2                  // spans per block
#define NSPANBLK (3 * NSPAN / SPB)   // 1536

typedef float f4 __attribute__((ext_vector_type(4)));

__device__ __forceinline__ f4 ld4(const float* p) {
    return *(const f4*)p;
}
__device__ __forceinline__ void st4(float* p, f4 v) {
    *(f4*)p = v;   // regular write-back store: lands in L2, HBM writeback is lazy
}

__global__ __launch_bounds__(128) void diff_extract_kernel(
    const float* __restrict__ topic_reps,   // (B, T, 2hD)
    const float* __restrict__ word_reps,    // (B, S, 2hD)
    const int*   __restrict__ topic_lens,   // (B,)
    const int*   __restrict__ para_spans,   // (B, N, 3)
    const int*   __restrict__ shell_spans,  // (B, N, 3)
    const int*   __restrict__ x_spans,      // (B, N, 3)
    float*       __restrict__ out)
{
    const int blk = blockIdx.x;
    const int t   = threadIdx.x;
    const int w   = t * 4;                  // float offset within 512-float half

    if (blk < NSPANBLK) {
        // Each block handles SPB consecutive spans of one set.
        // Output set order: para, span(=shell), adu(=x).
        const int g    = blk * SPB;          // first global span id
        const int set  = g / NSPAN;
        const int idx0 = g - set * NSPAN;    // first idx within set
        const int* spans = (set == 0) ? para_spans
                         : (set == 1) ? shell_spans
                                      : x_spans;

        // Indices for both spans (contiguous 6 ints -> scalar loads).
        const int e0  = spans[idx0 * 3 + 0];
        const int s0  = spans[idx0 * 3 + 1];
        const int en0 = spans[idx0 * 3 + 2];
        const int e1  = spans[idx0 * 3 + 3];
        const int s1  = spans[idx0 * 3 + 4];
        const int en1 = spans[idx0 * 3 + 5];

        const float* b0 = word_reps + (size_t)e0 * (S_ * D2_);
        const float* b1 = word_reps + (size_t)e1 * (S_ * D2_);
        float* o = out + TOPIC_OUT + (size_t)g * SPAN_OUT;

        // Issue all 8 independent 16B gathers before any store (MLP=8).
        const f4 sf0 = ld4(b0 + (size_t)(s0 - 1)  * D2_ + w);
        const f4 ef0 = ld4(b0 + (size_t)en0       * D2_ + w);
        const f4 sb0 = ld4(b0 + (size_t)(en0 + 1) * D2_ + HD_ + w);
        const f4 eb0 = ld4(b0 + (size_t)s0        * D2_ + HD_ + w);
        const f4 sf1 = ld4(b1 + (size_t)(s1 - 1)  * D2_ + w);
        const f4 ef1 = ld4(b1 + (size_t)en1       * D2_ + w);
        const f4 sb1 = ld4(b1 + (size_t)(en1 + 1) * D2_ + HD_ + w);
        const f4 eb1 = ld4(b1 + (size_t)s1        * D2_ + HD_ + w);

        st4(o + w,                       ef0 - sf0);
        st4(o + HD_ + w,                 eb0 - sb0);
        st4(o + 2 * HD_ + w,             sf0);
        st4(o + 3 * HD_ + w,             sb0);
        st4(o + SPAN_OUT + w,            ef1 - sf1);
        st4(o + SPAN_OUT + HD_ + w,      eb1 - sb1);
        st4(o + SPAN_OUT + 2 * HD_ + w,  sf1);
        st4(o + SPAN_OUT + 3 * HD_ + w,  sb1);
    } else {
        // Topic end-extract: one block per batch row, 128 threads cover 1024 floats.
        const int b = blk - NSPANBLK;
        const int len = topic_lens[b];
        const float* tb = topic_reps + (size_t)b * (T_ * D2_);
        float* o = out + (size_t)b * D2_;
        const f4 f = ld4(tb + (size_t)(len - 1) * D2_ + w);
        const f4 g = ld4(tb + HD_ + w);
        st4(o + w, f);
        st4(o + HD_ + w, g);
    }
}

extern "C" void kernel_launch(void* const* d_in, const int* in_sizes, int n_in,
                              void* d_out, int out_size, void* d_ws, size_t ws_size,
                              hipStream_t stream) {
    const float* topic_reps  = (const float*)d_in[0];
    const float* word_reps   = (const float*)d_in[1];
    const int*   topic_lens  = (const int*)  d_in[2];
    const int*   para_spans  = (const int*)  d_in[3];
    const int*   x_spans     = (const int*)  d_in[4];
    const int*   shell_spans = (const int*)  d_in[5];
    float* out = (float*)d_out;

    const int nblocks = NSPANBLK + B_;  // 1552
    diff_extract_kernel<<<nblocks, 128, 0, stream>>>(
        topic_reps, word_reps, topic_lens,
        para_spans, shell_spans, x_spans, out);
}

// Round 6
// 10.806 us; speedup vs baseline: 1.1988x; 1.1988x over previous
//
#include <hip/hip_runtime.h>

// Problem constants (from setup_inputs)
#define B_    16
#define S_    2048
#define T_    128
#define HD_   512
#define D2_   1024   // 2*hD
#define N_    64
#define NSPAN (B_ * N_)          // 1024 spans per set
#define SPAN_OUT (4 * HD_)       // 2048 floats per span
#define TOPIC_OUT (B_ * D2_)     // 16384 floats
#define SPB   2                  // spans per block
#define NSPANBLK (3 * NSPAN / SPB)   // 1536

typedef float f4 __attribute__((ext_vector_type(4)));

__device__ __forceinline__ f4 ld4(const float* p) {
    return *(const f4*)p;
}
__device__ __forceinline__ void nt_store4(float* p, f4 v) {
    __builtin_nontemporal_store(v, (f4*)p);   // no write-allocate: skip L2 RFO
}

__global__ __launch_bounds__(256) void diff_extract_kernel(
    const float* __restrict__ topic_reps,   // (B, T, 2hD)
    const float* __restrict__ word_reps,    // (B, S, 2hD)
    const int*   __restrict__ topic_lens,   // (B,)
    const int*   __restrict__ para_spans,   // (B, N, 3)
    const int*   __restrict__ shell_spans,  // (B, N, 3)
    const int*   __restrict__ x_spans,      // (B, N, 3)
    float*       __restrict__ out)
{
    const int blk = blockIdx.x;
    const int t   = threadIdx.x;

    if (blk < NSPANBLK) {
        // 256 threads = 2 spans; thread's bit7 selects the span (sp uniform per wave).
        const int sp = t >> 7;               // 0 or 1
        const int w  = (t & 127) * 4;        // float offset within 512-float half

        const int g    = blk * SPB;          // first global span id
        const int set  = g / NSPAN;
        const int idx  = g - set * NSPAN + sp;
        const int* spans = (set == 0) ? para_spans
                         : (set == 1) ? shell_spans
                                      : x_spans;

        const int e  = spans[idx * 3 + 0];
        const int s  = spans[idx * 3 + 1];
        const int en = spans[idx * 3 + 2];

        const float* base = word_reps + (size_t)e * (S_ * D2_);
        float* o = out + TOPIC_OUT + (size_t)(g + sp) * SPAN_OUT;

        // 4 independent 16B gathers per thread (ILP=4), 4 waves/block (TLP x2).
        const f4 sf = ld4(base + (size_t)(s - 1)  * D2_ + w);
        const f4 ef = ld4(base + (size_t)en       * D2_ + w);
        const f4 sb = ld4(base + (size_t)(en + 1) * D2_ + HD_ + w);
        const f4 eb = ld4(base + (size_t)s        * D2_ + HD_ + w);

        nt_store4(o + w,            ef - sf);
        nt_store4(o + HD_ + w,      eb - sb);
        nt_store4(o + 2 * HD_ + w,  sf);
        nt_store4(o + 3 * HD_ + w,  sb);
    } else {
        // Topic end-extract: one block per batch row; 256 threads cover 1024 floats.
        const int b = blk - NSPANBLK;
        const int len = topic_lens[b];
        const float* tb = topic_reps + (size_t)b * (T_ * D2_);
        float* o = out + (size_t)b * D2_;
        if (t < 128) {
            const int w = t * 4;
            nt_store4(o + w, ld4(tb + (size_t)(len - 1) * D2_ + w));
        } else {
            const int w = (t - 128) * 4;
            nt_store4(o + HD_ + w, ld4(tb + HD_ + w));
        }
    }
}

extern "C" void kernel_launch(void* const* d_in, const int* in_sizes, int n_in,
                              void* d_out, int out_size, void* d_ws, size_t ws_size,
                              hipStream_t stream) {
    const float* topic_reps  = (const float*)d_in[0];
    const float* word_reps   = (const float*)d_in[1];
    const int*   topic_lens  = (const int*)  d_in[2];
    const int*   para_spans  = (const int*)  d_in[3];
    const int*   x_spans     = (const int*)  d_in[4];
    const int*   shell_spans = (const int*)  d_in[5];
    float* out = (float*)d_out;

    const int nblocks = NSPANBLK + B_;  // 1552
    diff_extract_kernel<<<nblocks, 256, 0, stream>>>(
        topic_reps, word_reps, topic_lens,
        para_spans, shell_spans, x_spans, out);
}